// Round 4
// baseline (528.819 us; speedup 1.0000x reference)
//
#include <hip/hip_runtime.h>

// Problem constants (fixed by the reference's setup_inputs)
#define BATCH   256
#define N_PER   4096
#define M_TOTAL (BATCH * N_PER)
#define EMBED   16
#define HID     32
#define NOTE    64
#define LSTM_D  64
#define T_LEN   128
#define LVLS    6
#define VOCAB   200

// ---------------------------------------------------------------------------
// ws layout:
//   meta[0..7]   bucket counts  (b0=kind0 leaves, b1=kind1 ptr, b2..b6=level1..5, b7=root)
//   meta[8..15]  bucket slot bases
//   slot2node    @ OFF_S2N  (4096)  slot -> node id (sorted by node id per bucket)
//   child_off    @ OFF_COFF (4097)  CSR offsets, node-indexed
//   child_idx    @ OFF_CIDX (4096)  CSR child entries as SLOTS
//   fn_pre  [BATCH][32]       @ FN_PRE_OFF
//   ptr_pre [BATCH*T_LEN][32] @ PTR_PRE_OFF
//   h       [M_TOTAL][32]     @ H_OFF   (slot-permuted: h[tree*4096 + slot])
// ---------------------------------------------------------------------------
#define OFF_S2N   16
#define OFF_COFF  (OFF_S2N + N_PER)
#define OFF_CIDX  (OFF_COFF + N_PER + 1)

#define FN_PRE_OFF   (256 * 1024)
#define PTR_PRE_OFF  (1024 * 1024)
#define H_OFF        (8ull * 1024 * 1024)

// ---------------------------------------------------------------------------
// Build: stable (node-id-sorted) bucket lists via per-bucket block scans,
// slot assignment, and children CSR with child entries stored as slots.
// ---------------------------------------------------------------------------
__global__ __launch_bounds__(1024) void build_structure(
    const int* __restrict__ kind, const int* __restrict__ height,
    const int* __restrict__ parent, int* __restrict__ meta)
{
    __shared__ int part[1024];
    __shared__ int tot[8];
    __shared__ int bases[8];
    __shared__ int n2s[N_PER];   // 16 KB
    __shared__ int deg[N_PER];   // 16 KB

    int t = threadIdx.x;
    int base4 = 4 * t;

    int myb[4];
    #pragma unroll
    for (int q = 0; q < 4; ++q) {
        int i = base4 + q;
        int hgt = height[i];
        int b;
        if (hgt > 0) b = 1 + hgt;                 // levels 1..5 -> 2..6, root(6) -> 7
        else         b = (kind[i] == 0) ? 0 : 1;  // leaves by kind
        if (b > 7) b = 7;
        myb[q] = b;
    }

    // stable per-bucket scan: exclusive offset of this thread within bucket b
    int exoff[8];
    for (int b = 0; b < 8; ++b) {
        int c = (myb[0] == b) + (myb[1] == b) + (myb[2] == b) + (myb[3] == b);
        part[t] = c;
        __syncthreads();
        for (int off = 1; off < 1024; off <<= 1) {
            int v = (t >= off) ? part[t - off] : 0;
            __syncthreads();
            part[t] += v;
            __syncthreads();
        }
        exoff[b] = part[t] - c;
        if (t == 1023) tot[b] = part[1023];
        __syncthreads();
    }
    if (t == 0) {
        int s = 0;
        for (int b = 0; b < 8; ++b) {
            bases[b] = s; meta[8 + b] = s; meta[b] = tot[b]; s += tot[b];
        }
    }
    __syncthreads();

    #pragma unroll
    for (int q = 0; q < 4; ++q) {
        int i = base4 + q;
        int b = myb[q];
        int slot = bases[b] + exoff[b];
        exoff[b] += 1;
        n2s[i] = slot;
        meta[OFF_S2N + slot] = i;
    }

    // degree count (first tree; parent[0]==0 self-loop skipped)
    #pragma unroll
    for (int q = 0; q < 4; ++q) deg[base4 + q] = 0;
    __syncthreads();
    #pragma unroll
    for (int q = 0; q < 4; ++q) {
        int i = base4 + q;
        if (i != 0) atomicAdd(&deg[parent[i]], 1);
    }
    __syncthreads();

    // exclusive prefix over deg[4096]
    int d0 = deg[base4], d1 = deg[base4 + 1], d2 = deg[base4 + 2], d3 = deg[base4 + 3];
    part[t] = d0 + d1 + d2 + d3;
    __syncthreads();
    for (int off = 1; off < 1024; off <<= 1) {
        int v = (t >= off) ? part[t - off] : 0;
        __syncthreads();
        part[t] += v;
        __syncthreads();
    }
    int ex = part[t] - (d0 + d1 + d2 + d3);
    int o0 = ex, o1 = ex + d0, o2 = o1 + d1, o3 = o2 + d2;
    deg[base4] = o0; deg[base4 + 1] = o1; deg[base4 + 2] = o2; deg[base4 + 3] = o3;
    meta[OFF_COFF + base4]     = o0;
    meta[OFF_COFF + base4 + 1] = o1;
    meta[OFF_COFF + base4 + 2] = o2;
    meta[OFF_COFF + base4 + 3] = o3;
    if (t == 1023) meta[OFF_COFF + N_PER] = o3 + d3;
    __syncthreads();

    // fill CSR with child SLOTS, using deg[] as cursor
    #pragma unroll
    for (int q = 0; q < 4; ++q) {
        int i = base4 + q;
        if (i == 0) continue;
        int pos = atomicAdd(&deg[parent[i]], 1);
        meta[OFF_CIDX + pos] = n2s[i];
    }
}

// ---------------------------------------------------------------------------
// Prep: fn_pre, ptr_pre GEMM, leaf h (coalesced slot-ordered writes).
// ---------------------------------------------------------------------------
__global__ __launch_bounds__(256) void prep_kernel(
    const int* __restrict__ meta,
    const int* __restrict__ tok_a, const int* __restrict__ tok_b,
    const float* __restrict__ first_notes, const float* __restrict__ lstm_out,
    const float* __restrict__ embedding,
    const float* __restrict__ leaf_w1, const float* __restrict__ leaf_b1,
    const float* __restrict__ leaf_w2, const float* __restrict__ leaf_b2,
    const float* __restrict__ ptr_w, const float* __restrict__ ptr_b,
    float* __restrict__ fn_pre, float* __restrict__ ptr_pre,
    float* __restrict__ h)
{
    __shared__ float semb[VOCAB * EMBED];   // 12.8 KB
    for (int i = threadIdx.x; i < VOCAB * EMBED; i += 256) semb[i] = embedding[i];
    __syncthreads();

    int ngroups = (gridDim.x * blockDim.x) >> 5;
    int gid     = (blockIdx.x * blockDim.x + threadIdx.x) >> 5;
    int lane    = threadIdx.x & 31;

    // --- A: fn_pre[tree] = ptr_b + first_notes[tree] @ ptr_w[0:64] ---
    for (int r = gid; r < BATCH; r += ngroups) {
        const float* fn = first_notes + (size_t)r * NOTE;
        float v = ptr_b[lane];
        #pragma unroll
        for (int kk = 0; kk < NOTE; ++kk) v += fn[kk] * ptr_w[kk * HID + lane];
        fn_pre[(size_t)r * HID + lane] = v;
    }

    // --- B: ptr_pre[r] = lstm_out_flat[r] @ ptr_w[64:128] ---
    {
        int nB = BATCH * T_LEN;
        for (int r = gid; r < nB; r += ngroups) {
            const float* lo = lstm_out + (size_t)r * LSTM_D;
            float v = 0.0f;
            #pragma unroll
            for (int kk = 0; kk < LSTM_D; ++kk)
                v += lo[kk] * ptr_w[(NOTE + kk) * HID + lane];
            ptr_pre[(size_t)r * HID + lane] = v;
        }
    }

    // --- C: leaf h, slots [0, c0) per tree ---
    {
        int c0 = meta[0];
        int nC = c0 * BATCH;
        const int* s2n = meta + OFF_S2N;
        float w1a[EMBED], w1b[EMBED], w2c[HID];
        #pragma unroll
        for (int kk = 0; kk < EMBED; ++kk) {
            w1a[kk] = leaf_w1[kk * HID + lane];
            w1b[kk] = leaf_w1[(EMBED + kk) * HID + lane];
        }
        #pragma unroll
        for (int kk = 0; kk < HID; ++kk) w2c[kk] = leaf_w2[kk * HID + lane];
        float b1 = leaf_b1[lane], b2 = leaf_b2[lane];

        for (int r = gid; r < nC; r += ngroups) {
            int tree = r / c0;
            int j    = r - tree * c0;
            int node = s2n[j];                    // bucket 0 base is 0
            int gn   = tree * N_PER + node;
            const float4* ea = (const float4*)(semb + tok_a[gn] * EMBED);
            const float4* eb = (const float4*)(semb + tok_b[gn] * EMBED);
            float hid = b1;
            #pragma unroll
            for (int q = 0; q < 4; ++q) {
                float4 a = ea[q];
                hid += a.x * w1a[4*q] + a.y * w1a[4*q+1] + a.z * w1a[4*q+2] + a.w * w1a[4*q+3];
            }
            #pragma unroll
            for (int q = 0; q < 4; ++q) {
                float4 b = eb[q];
                hid += b.x * w1b[4*q] + b.y * w1b[4*q+1] + b.z * w1b[4*q+2] + b.w * w1b[4*q+3];
            }
            float v = b2;
            #pragma unroll
            for (int kk = 0; kk < HID; ++kk) v += __shfl(hid, kk, 32) * w2c[kk];
            h[((size_t)tree * N_PER + j) * HID + lane] = v;   // slot j
        }
    }
}

// ---------------------------------------------------------------------------
// Ptr scatter: h[slot] = fn_pre[tree] + ptr_pre[tree*T_LEN + t], slots [c0,c0+c1)
// ---------------------------------------------------------------------------
__global__ __launch_bounds__(256) void ptr_scatter_kernel(
    const int* __restrict__ meta, const int* __restrict__ ptr_time,
    const float* __restrict__ fn_pre, const float* __restrict__ ptr_pre,
    float* __restrict__ h)
{
    int c1   = meta[1];
    int base = meta[9];
    int tot  = c1 * BATCH;
    int ngroups = (gridDim.x * blockDim.x) >> 5;
    int gid     = (blockIdx.x * blockDim.x + threadIdx.x) >> 5;
    int lane    = threadIdx.x & 31;
    const int* s2n = meta + OFF_S2N;

    for (int r = gid; r < tot; r += ngroups) {
        int tree = r / c1;
        int j    = r - tree * c1;
        int slot = base + j;
        int node = s2n[slot];
        int gn   = tree * N_PER + node;
        int tt   = ptr_time[gn];
        float v = fn_pre[(size_t)tree * HID + lane]
                + ptr_pre[((size_t)tree * T_LEN + tt) * HID + lane];
        h[((size_t)tree * N_PER + slot) * HID + lane] = v;
    }
}

// ---------------------------------------------------------------------------
// Level pass (levels 1..5), recomputing the embedding half on the fly:
//   h[slot] = relu(node_b + [ea,eb]@node_w[0:32] + csum@node_w[32:64])
// ---------------------------------------------------------------------------
__global__ __launch_bounds__(256) void level_kernel(
    const int* __restrict__ meta,
    const int* __restrict__ tok_a, const int* __restrict__ tok_b,
    const float* __restrict__ embedding,
    const float* __restrict__ node_w, const float* __restrict__ node_b,
    float* __restrict__ h, int lvl)
{
    __shared__ float semb[VOCAB * EMBED];
    for (int i = threadIdx.x; i < VOCAB * EMBED; i += 256) semb[i] = embedding[i];
    __syncthreads();

    int cnt  = meta[1 + lvl];        // bucket 1+lvl
    int base = meta[8 + 1 + lvl];
    int tot  = cnt * BATCH;
    int ngroups = (gridDim.x * blockDim.x) >> 5;
    int gid     = (blockIdx.x * blockDim.x + threadIdx.x) >> 5;
    int lane    = threadIdx.x & 31;

    const int* s2n       = meta + OFF_S2N;
    const int* child_off = meta + OFF_COFF;
    const int* child_idx = meta + OFF_CIDX;

    float wa[EMBED], wb[EMBED], wc[HID];
    #pragma unroll
    for (int kk = 0; kk < EMBED; ++kk) {
        wa[kk] = node_w[kk * HID + lane];
        wb[kk] = node_w[(EMBED + kk) * HID + lane];
    }
    #pragma unroll
    for (int kk = 0; kk < HID; ++kk) wc[kk] = node_w[(2 * EMBED + kk) * HID + lane];
    float nb = node_b[lane];

    for (int r = gid; r < tot; r += ngroups) {
        int tree = r / cnt;
        int j    = r - tree * cnt;
        int slot = base + j;
        int node = s2n[slot];
        int gn   = tree * N_PER + node;

        const float* hb = h + (size_t)tree * N_PER * HID;
        float csum = 0.0f;
        int e = child_off[node], e1 = child_off[node + 1];
        for (; e + 1 < e1; e += 2) {
            float a0 = hb[(size_t)child_idx[e]     * HID + lane];
            float a1 = hb[(size_t)child_idx[e + 1] * HID + lane];
            csum += a0 + a1;
        }
        if (e < e1) csum += hb[(size_t)child_idx[e] * HID + lane];

        const float4* ea = (const float4*)(semb + tok_a[gn] * EMBED);
        const float4* eb = (const float4*)(semb + tok_b[gn] * EMBED);
        float v = nb;
        #pragma unroll
        for (int q = 0; q < 4; ++q) {
            float4 a = ea[q];
            v += a.x * wa[4*q] + a.y * wa[4*q+1] + a.z * wa[4*q+2] + a.w * wa[4*q+3];
        }
        #pragma unroll
        for (int q = 0; q < 4; ++q) {
            float4 b = eb[q];
            v += b.x * wb[4*q] + b.y * wb[4*q+1] + b.z * wb[4*q+2] + b.w * wb[4*q+3];
        }
        #pragma unroll
        for (int kk = 0; kk < HID; ++kk)
            v += __shfl(csum, kk, 32) * wc[kk];
        v = fmaxf(v, 0.0f);
        h[((size_t)tree * N_PER + slot) * HID + lane] = v;
    }
}

// ---------------------------------------------------------------------------
// Final (one block per tree): gather root children (8 groups), finish root h,
// FF head -> out[tree].
// ---------------------------------------------------------------------------
__global__ __launch_bounds__(256) void final_kernel(
    const int* __restrict__ meta,
    const int* __restrict__ tok_a, const int* __restrict__ tok_b,
    const float* __restrict__ embedding,
    const float* __restrict__ node_w, const float* __restrict__ node_b,
    const float* __restrict__ h,
    const float* __restrict__ ff_w1, const float* __restrict__ ff_b1,
    const float* __restrict__ ff_w2, const float* __restrict__ ff_b2,
    const float* __restrict__ tail_w, const float* __restrict__ tail_b,
    float* __restrict__ out)
{
    __shared__ float red[8][HID];
    int tree = blockIdx.x;
    int grp  = threadIdx.x >> 5;
    int lane = threadIdx.x & 31;

    const int* child_off = meta + OFF_COFF;
    const int* child_idx = meta + OFF_CIDX;
    int s0 = child_off[0], e0 = child_off[1];   // root = node 0

    const float* hb = h + (size_t)tree * N_PER * HID;
    float cs = 0.0f;
    for (int e = s0 + grp; e < e0; e += 8)
        cs += hb[(size_t)child_idx[e] * HID + lane];
    red[grp][lane] = cs;
    __syncthreads();

    if (grp == 0) {
        float csum = red[0][lane];
        #pragma unroll
        for (int g = 1; g < 8; ++g) csum += red[g][lane];

        int gn = tree * N_PER;   // root node 0
        const float* ea = embedding + (size_t)tok_a[gn] * EMBED;
        const float* eb = embedding + (size_t)tok_b[gn] * EMBED;
        float v = node_b[lane];
        #pragma unroll
        for (int kk = 0; kk < EMBED; ++kk) v += ea[kk] * node_w[kk * HID + lane];
        #pragma unroll
        for (int kk = 0; kk < EMBED; ++kk) v += eb[kk] * node_w[(EMBED + kk) * HID + lane];
        #pragma unroll
        for (int kk = 0; kk < HID; ++kk)
            v += __shfl(csum, kk, 32) * node_w[(2 * EMBED + kk) * HID + lane];
        v = fmaxf(v, 0.0f);

        float f1 = ff_b1[lane];
        #pragma unroll
        for (int kk = 0; kk < HID; ++kk) f1 += __shfl(v, kk, 32) * ff_w1[kk * HID + lane];
        float f2 = ff_b2[lane];
        #pragma unroll
        for (int kk = 0; kk < HID; ++kk) f2 += __shfl(f1, kk, 32) * ff_w2[kk * HID + lane];

        float contrib = f2 * tail_w[lane];
        #pragma unroll
        for (int off = 16; off > 0; off >>= 1) contrib += __shfl_down(contrib, off, 32);
        if (lane == 0) out[tree] = contrib + tail_b[0];
    }
}

extern "C" void kernel_launch(void* const* d_in, const int* in_sizes, int n_in,
                              void* d_out, int out_size, void* d_ws, size_t ws_size,
                              hipStream_t stream) {
    const int*   kind        = (const int*)d_in[0];
    const int*   height      = (const int*)d_in[1];
    const int*   parent      = (const int*)d_in[2];
    const int*   tok_a       = (const int*)d_in[3];
    const int*   tok_b       = (const int*)d_in[4];
    const int*   ptr_time    = (const int*)d_in[5];
    const float* first_notes = (const float*)d_in[6];
    const float* lstm_out    = (const float*)d_in[7];
    const float* embedding   = (const float*)d_in[8];
    const float* leaf_w1     = (const float*)d_in[9];
    const float* leaf_b1     = (const float*)d_in[10];
    const float* leaf_w2     = (const float*)d_in[11];
    const float* leaf_b2     = (const float*)d_in[12];
    const float* node_w      = (const float*)d_in[13];
    const float* node_b      = (const float*)d_in[14];
    const float* ptr_w       = (const float*)d_in[15];
    const float* ptr_b       = (const float*)d_in[16];
    const float* ff_w1       = (const float*)d_in[17];
    const float* ff_b1       = (const float*)d_in[18];
    const float* ff_w2       = (const float*)d_in[19];
    const float* ff_b2       = (const float*)d_in[20];
    const float* tail_w      = (const float*)d_in[21];
    const float* tail_b      = (const float*)d_in[22];

    char* ws = (char*)d_ws;
    int*   meta    = (int*)ws;
    float* fn_pre  = (float*)(ws + FN_PRE_OFF);
    float* ptr_pre = (float*)(ws + PTR_PRE_OFF);
    float* h       = (float*)(ws + H_OFF);

    build_structure<<<1, 1024, 0, stream>>>(kind, height, parent, meta);

    prep_kernel<<<2048, 256, 0, stream>>>(
        meta, tok_a, tok_b, first_notes, lstm_out, embedding,
        leaf_w1, leaf_b1, leaf_w2, leaf_b2, ptr_w, ptr_b,
        fn_pre, ptr_pre, h);

    ptr_scatter_kernel<<<512, 256, 0, stream>>>(meta, ptr_time, fn_pre, ptr_pre, h);

    for (int lvl = 1; lvl <= 5; ++lvl) {
        level_kernel<<<2048, 256, 0, stream>>>(
            meta, tok_a, tok_b, embedding, node_w, node_b, h, lvl);
    }

    final_kernel<<<BATCH, 256, 0, stream>>>(
        meta, tok_a, tok_b, embedding, node_w, node_b, h,
        ff_w1, ff_b1, ff_w2, ff_b2, tail_w, tail_b, (float*)d_out);
}